// Round 2
// baseline (1043.842 us; speedup 1.0000x reference)
//
#include <hip/hip_runtime.h>
#include <hip/hip_bf16.h>

typedef __attribute__((ext_vector_type(8))) short bx8;
typedef __attribute__((ext_vector_type(4))) short sx4;
typedef __attribute__((ext_vector_type(4))) float fx4;

#define D_   1024
#define H_   8
#define E_   16
#define HD_  128
#define I_   512
#define M8_  8192      // BS*L
#define T_   65536     // M8*H

__device__ inline float bf2f(short u) {
  unsigned int x = ((unsigned int)(unsigned short)u) << 16;
  return __builtin_bit_cast(float, x);
}
__device__ inline short f2bf(float f) {
  __hip_bfloat16 h = __float2bfloat16(f);
  return __builtin_bit_cast(short, h);
}

__device__ inline void gload_lds16(const void* g, void* l) {
  __builtin_amdgcn_global_load_lds(
      (const __attribute__((address_space(1))) void*)g,
      (__attribute__((address_space(3))) void*)l, 16, 0, 0);
}

__device__ inline fx4 mfma16(bx8 a, bx8 b, fx4 c) {
  return __builtin_amdgcn_mfma_f32_16x16x32_bf16(a, b, c, 0, 0, 0);
}

// ---------------- conversions ----------------

__global__ __launch_bounds__(256) void cvt_bf16_k(const float* __restrict__ src,
                                                  __hip_bfloat16* __restrict__ dst) {
  int i = blockIdx.x * 256 + threadIdx.x;
  float4 v = *(const float4*)&src[(size_t)i * 4];
  sx4 o;
  o[0] = f2bf(v.x); o[1] = f2bf(v.y); o[2] = f2bf(v.z); o[3] = f2bf(v.w);
  *(sx4*)((short*)dst + (size_t)i * 4) = o;
}

// batched transpose+convert: dst[b][c][r] = src[b][r][c]
__global__ __launch_bounds__(256) void tcvt(const float* __restrict__ src,
                                            __hip_bfloat16* __restrict__ dst,
                                            int R, int C) {
  __shared__ float tile[32][33];
  int tx = threadIdx.x & 31, ty = threadIdx.x >> 5;
  int r0 = blockIdx.y * 32, c0 = blockIdx.x * 32;
  const float* s = src + (size_t)blockIdx.z * R * C;
  __hip_bfloat16* d = dst + (size_t)blockIdx.z * R * C;
#pragma unroll
  for (int i = ty; i < 32; i += 8) tile[i][tx] = s[(size_t)(r0 + i) * C + c0 + tx];
  __syncthreads();
#pragma unroll
  for (int i = ty; i < 32; i += 8)
    d[(size_t)(c0 + i) * R + r0 + tx] = __float2bfloat16(tile[tx][i]);
}

// ---------------- routing (exact fp32 path) ----------------

// Wre[d][eta*16+e] = sum_c Wm[d][eta*128+c] * emb[c][e]
__global__ __launch_bounds__(128) void build_wre(const float* __restrict__ Wm,
                                                 const float* __restrict__ bm,
                                                 const float* __restrict__ emb,
                                                 float* __restrict__ Wre,
                                                 float* __restrict__ rbias) {
  __shared__ float wrow[1024];
  __shared__ float embs[2048];
  int tid = threadIdx.x;
  int d = blockIdx.x;
  for (int i = tid; i < 2048; i += 128) embs[i] = emb[i];
  for (int i = tid; i < 1024; i += 128) wrow[i] = Wm[(size_t)d * 1024 + i];
  __syncthreads();
  int eta = tid >> 4, e = tid & 15;
  float acc = 0.f;
  for (int c = 0; c < 128; ++c) acc = fmaf(wrow[eta * 128 + c], embs[c * 16 + e], acc);
  Wre[(size_t)d * 128 + tid] = acc;
  if (blockIdx.x == 0) {
    float b = 0.f;
    for (int c = 0; c < 128; ++c) b = fmaf(bm[eta * 128 + c], embs[c * 16 + e], b);
    rbias[tid] = b;
  }
}

// logits[M8][128] = x[M8][1024] @ Wre[1024][128] + rbias  (fp32)
__global__ __launch_bounds__(256) void route_gemm(const float* __restrict__ x,
                                                  const float* __restrict__ Wre,
                                                  const float* __restrict__ rbias,
                                                  float* __restrict__ logits) {
  __shared__ float xs[32][128];
  int tid = threadIdx.x;
  int n = tid & 127, half = tid >> 7;
  int row0 = blockIdx.x * 32;
  float acc[16];
#pragma unroll
  for (int i = 0; i < 16; ++i) acc[i] = 0.f;
  for (int k0 = 0; k0 < 1024; k0 += 128) {
    __syncthreads();
#pragma unroll
    for (int j = 0; j < 4; ++j) {
      int i4 = tid * 4 + j * 1024;
      int row = i4 >> 7, col = i4 & 127;
      *(float4*)&xs[row][col] = *(const float4*)&x[(size_t)(row0 + row) * 1024 + k0 + col];
    }
    __syncthreads();
    for (int d4 = 0; d4 < 128; d4 += 4) {
      float w0 = Wre[(size_t)(k0 + d4 + 0) * 128 + n];
      float w1 = Wre[(size_t)(k0 + d4 + 1) * 128 + n];
      float w2 = Wre[(size_t)(k0 + d4 + 2) * 128 + n];
      float w3 = Wre[(size_t)(k0 + d4 + 3) * 128 + n];
#pragma unroll
      for (int i = 0; i < 16; ++i) {
        float4 xv = *(const float4*)&xs[half * 16 + i][d4];
        acc[i] = fmaf(xv.x, w0, acc[i]);
        acc[i] = fmaf(xv.y, w1, acc[i]);
        acc[i] = fmaf(xv.z, w2, acc[i]);
        acc[i] = fmaf(xv.w, w3, acc[i]);
      }
    }
  }
  float rb = rbias[n];
#pragma unroll
  for (int i = 0; i < 16; ++i)
    logits[(size_t)(row0 + half * 16 + i) * 128 + n] = acc[i] + rb;
}

// per sub-token softmax + top-2 + grouping lists
__global__ __launch_bounds__(256) void route_topk(const float* __restrict__ logits,
                                                  float* __restrict__ topw,
                                                  int* __restrict__ list,
                                                  int* __restrict__ cnt) {
  int s = blockIdx.x * 256 + threadIdx.x;
  const float* lp = logits + (size_t)(s >> 3) * 128 + (s & 7) * 16;
  float v[16];
#pragma unroll
  for (int j = 0; j < 4; ++j) {
    float4 t = *(const float4*)&lp[j * 4];
    v[j * 4 + 0] = t.x; v[j * 4 + 1] = t.y; v[j * 4 + 2] = t.z; v[j * 4 + 3] = t.w;
  }
  float v1 = -1e30f, v2 = -1e30f; int i1 = 0, i2 = 0;
#pragma unroll
  for (int e = 0; e < 16; ++e) {
    float val = v[e];
    if (val > v1) { v2 = v1; i2 = i1; v1 = val; i1 = e; }
    else if (val > v2) { v2 = val; i2 = e; }
  }
  float sum = 0.f;
#pragma unroll
  for (int e = 0; e < 16; ++e) sum += expf(v[e] - v1);
  topw[(size_t)2 * s + 0] = 1.0f / sum;
  topw[(size_t)2 * s + 1] = expf(v2 - v1) / sum;
  int p1 = atomicAdd(&cnt[i1], 1); list[(size_t)i1 * T_ + p1] = 2 * s;
  int p2 = atomicAdd(&cnt[i2], 1); list[(size_t)i2 * T_ + p2] = 2 * s + 1;
}

// ---------------- bf16 MFMA GEMM: C = A @ BT^T (+bias), BT is [N][K] ----------------

template <int OUTF32>
__global__ __launch_bounds__(256) void gemm_bt(const __hip_bfloat16* __restrict__ A,
                                               const __hip_bfloat16* __restrict__ BT,
                                               const float* __restrict__ bias,
                                               void* __restrict__ Cout,
                                               int M, int N, int Kd) {
  __shared__ __hip_bfloat16 As[128 * 64];
  __shared__ __hip_bfloat16 Bs[128 * 64];
  int tid = threadIdx.x;
  int lane = tid & 63, w = tid >> 6;
  int nbn = N >> 7;
  int bm = blockIdx.x / nbn, bn = blockIdx.x % nbn;
  int wm = w >> 1, wn = w & 1;
  int r = lane & 15, g = lane >> 4;
  const fx4 fz = {0.f, 0.f, 0.f, 0.f};
  fx4 acc[4][4];
#pragma unroll
  for (int m = 0; m < 4; ++m)
#pragma unroll
    for (int n = 0; n < 4; ++n) acc[m][n] = fz;
  const short* AsS = (const short*)As;
  const short* BsS = (const short*)Bs;
  for (int k0 = 0; k0 < Kd; k0 += 64) {
    __syncthreads();
#pragma unroll
    for (int i = 0; i < 4; ++i) {
      int c = i * 256 + w * 64 + lane;
      int row = c >> 3, ko = (c & 7) * 8;
      gload_lds16(A + (size_t)(bm * 128 + row) * Kd + k0 + ko,
                  (void*)(As + (size_t)(i * 256 + w * 64) * 8));
    }
#pragma unroll
    for (int i = 0; i < 4; ++i) {
      int c = i * 256 + w * 64 + lane;
      int row = c >> 3, ko = (c & 7) * 8;
      gload_lds16(BT + (size_t)(bn * 128 + row) * Kd + k0 + ko,
                  (void*)(Bs + (size_t)(i * 256 + w * 64) * 8));
    }
    __syncthreads();
#pragma unroll
    for (int kb = 0; kb < 2; ++kb) {
      bx8 af[4], bfr[4];
#pragma unroll
      for (int m = 0; m < 4; ++m)
        af[m] = *(const bx8*)(AsS + (wm * 64 + m * 16 + r) * 64 + kb * 32 + g * 8);
#pragma unroll
      for (int n = 0; n < 4; ++n)
        bfr[n] = *(const bx8*)(BsS + (wn * 64 + n * 16 + r) * 64 + kb * 32 + g * 8);
#pragma unroll
      for (int m = 0; m < 4; ++m)
#pragma unroll
        for (int n = 0; n < 4; ++n)
          acc[m][n] = mfma16(af[m], bfr[n], acc[m][n]);
    }
  }
#pragma unroll
  for (int n = 0; n < 4; ++n) {
    int col = bn * 128 + wn * 64 + n * 16 + r;
    float bv = bias[col];
#pragma unroll
    for (int m = 0; m < 4; ++m) {
      int rowb = bm * 128 + wm * 64 + m * 16 + g * 4;
#pragma unroll
      for (int ri = 0; ri < 4; ++ri) {
        float val = acc[m][n][ri] + bv;
        if (OUTF32) ((float*)Cout)[(size_t)(rowb + ri) * N + col] = val;
        else ((__hip_bfloat16*)Cout)[(size_t)(rowb + ri) * N + col] = __float2bfloat16(val);
      }
    }
  }
}

// ---------------- fused per-expert MLP (gather -> GEMM -> gelu -> GEMM -> scatter) ----------------

__global__ __launch_bounds__(256) void expert_mlp(const __hip_bfloat16* __restrict__ h,
                                                  const __hip_bfloat16* __restrict__ W1T,
                                                  const __hip_bfloat16* __restrict__ W2T,
                                                  const float* __restrict__ b1,
                                                  const float* __restrict__ b2,
                                                  const float* __restrict__ topw,
                                                  const int* __restrict__ list,
                                                  const int* __restrict__ cnt,
                                                  __hip_bfloat16* __restrict__ eo) {
  int e = blockIdx.x >> 10, tile = blockIdx.x & 1023;
  int cnt_e = cnt[e];
  int base = tile * 64;
  if (base >= cnt_e) return;
  __shared__ __hip_bfloat16 As[64 * 128];     // swizzled, 16KB
  __shared__ __hip_bfloat16 Hc[4][16 * 128];  // per-wave hmid chunk, swizzled, 16KB
  __shared__ int pids[64];
  __shared__ float wrow[64];
  int tid = threadIdx.x, lane = tid & 63, wv = tid >> 6;
  if (tid < 64) {
    int idx = base + tid;
    int p = (idx < cnt_e) ? list[(size_t)e * T_ + idx] : -1;
    pids[tid] = p;
    wrow[tid] = (p >= 0) ? topw[p] : 0.f;
  }
  __syncthreads();
  const short* hS = (const short*)h;
  for (int c = tid; c < 1024; c += 256) {
    int row = c >> 4, o = c & 15;
    int p = pids[row];
    int st = (p >= 0) ? (p >> 1) : 0;
    bx8 v = *(const bx8*)(hS + (size_t)st * 128 + o * 8);
    int db = row * 256 + ((o * 16) ^ ((row & 7) << 4));
    *(bx8*)((char*)As + db) = v;
  }
  __syncthreads();
  int r = lane & 15, g = lane >> 4;
  const short* W1S = (const short*)(W1T + (size_t)e * I_ * HD_);
  const short* W2S = (const short*)(W2T + (size_t)e * HD_ * I_);
  const fx4 fz = {0.f, 0.f, 0.f, 0.f};
  fx4 acc2[8];
#pragma unroll
  for (int i = 0; i < 8; ++i) acc2[i] = fz;
  short* HcS = (short*)Hc[wv];
  int arow = wv * 16 + r;
  for (int c4 = 0; c4 < 4; ++c4) {
    fx4 acc1[8];
#pragma unroll
    for (int i = 0; i < 8; ++i) acc1[i] = fz;
#pragma unroll
    for (int kb = 0; kb < 4; ++kb) {
      int ab = arow * 256 + (((kb * 32 + g * 8) * 2) ^ ((arow & 7) << 4));
      bx8 a = *(const bx8*)((const char*)As + ab);
#pragma unroll
      for (int n = 0; n < 8; ++n) {
        bx8 b = *(const bx8*)(W1S + (size_t)(c4 * 128 + n * 16 + r) * 128 + kb * 32 + g * 8);
        acc1[n] = mfma16(a, b, acc1[n]);
      }
    }
    // gelu (exact erf) + write hmid chunk to wave-private LDS
#pragma unroll
    for (int n = 0; n < 8; ++n) {
      int col = c4 * 128 + n * 16 + r;
      float b1v = b1[(size_t)e * I_ + col];
      int hcol = n * 16 + r;
#pragma unroll
      for (int ri = 0; ri < 4; ++ri) {
        float xg = acc1[n][ri] + b1v;
        float ge = 0.5f * xg * (1.f + erff(xg * 0.70710678118f));
        int hrow = g * 4 + ri;
        int hb = hrow * 256 + ((hcol * 2) ^ ((hrow & 7) << 4));
        *(short*)((char*)HcS + hb) = f2bf(ge);
      }
    }
    // GEMM2 partial accumulate over this i-chunk (wave-private, no barrier needed)
#pragma unroll
    for (int kb = 0; kb < 4; ++kb) {
      int ab = r * 256 + (((kb * 32 + g * 8) * 2) ^ ((r & 7) << 4));
      bx8 a = *(const bx8*)((const char*)HcS + ab);
#pragma unroll
      for (int n = 0; n < 8; ++n) {
        bx8 b = *(const bx8*)(W2S + (size_t)(n * 16 + r) * 512 + c4 * 128 + kb * 32 + g * 8);
        acc2[n] = mfma16(a, b, acc2[n]);
      }
    }
  }
#pragma unroll
  for (int n = 0; n < 8; ++n) {
    int col = n * 16 + r;
    float b2v = b2[(size_t)e * HD_ + col];
#pragma unroll
    for (int ri = 0; ri < 4; ++ri) {
      int row = wv * 16 + g * 4 + ri;
      int p = pids[row];
      if (p >= 0) {
        float v = (acc2[n][ri] + b2v) * wrow[row];
        ((__hip_bfloat16*)eo)[(size_t)p * 128 + col] = __float2bfloat16(v);
      }
    }
  }
}

// comb[s][:] = eo[2s][:] + eo[2s+1][:]   (weights already applied)
__global__ __launch_bounds__(256) void combine_k(const __hip_bfloat16* __restrict__ eo,
                                                 __hip_bfloat16* __restrict__ comb) {
  int t = blockIdx.x * 256 + threadIdx.x;
  int s = t >> 4, oo = (t & 15) * 8;
  const short* eS = (const short*)eo;
  bx8 a = *(const bx8*)(eS + (size_t)s * 256 + oo);
  bx8 b = *(const bx8*)(eS + (size_t)s * 256 + 128 + oo);
  bx8 ov;
#pragma unroll
  for (int j = 0; j < 8; ++j) ov[j] = f2bf(bf2f(a[j]) + bf2f(b[j]));
  *(bx8*)((short*)comb + (size_t)s * 128 + oo) = ov;
}

// ---------------- host ----------------

extern "C" void kernel_launch(void* const* d_in, const int* in_sizes, int n_in,
                              void* d_out, int out_size, void* d_ws, size_t ws_size,
                              hipStream_t stream) {
  const float* x   = (const float*)d_in[0];
  const float* Wm  = (const float*)d_in[1];
  const float* bm  = (const float*)d_in[2];
  const float* emb = (const float*)d_in[3];
  const float* W1  = (const float*)d_in[4];
  const float* b1  = (const float*)d_in[5];
  const float* W2  = (const float*)d_in[6];
  const float* b2  = (const float*)d_in[7];
  const float* Wo  = (const float*)d_in[8];
  const float* bo  = (const float*)d_in[9];

  char* ws = (char*)d_ws;
  size_t off = 0;
  auto alloc = [&](size_t b) { size_t r = off; off += (b + 255) & ~(size_t)255; return r; };
  __hip_bfloat16* xb   = (__hip_bfloat16*)(ws + alloc((size_t)M8_ * D_ * 2));
  __hip_bfloat16* WmT  = (__hip_bfloat16*)(ws + alloc((size_t)D_ * D_ * 2));
  __hip_bfloat16* WoT  = (__hip_bfloat16*)(ws + alloc((size_t)D_ * D_ * 2));
  __hip_bfloat16* W1T  = (__hip_bfloat16*)(ws + alloc((size_t)E_ * HD_ * I_ * 2));
  __hip_bfloat16* W2T  = (__hip_bfloat16*)(ws + alloc((size_t)E_ * HD_ * I_ * 2));
  __hip_bfloat16* hb   = (__hip_bfloat16*)(ws + alloc((size_t)M8_ * D_ * 2));
  float* Wre    = (float*)(ws + alloc((size_t)D_ * 128 * 4));
  float* rbias  = (float*)(ws + alloc(512));
  float* logits = (float*)(ws + alloc((size_t)T_ * 16 * 4));
  float* topw   = (float*)(ws + alloc((size_t)T_ * 2 * 4));
  int*   cnt    = (int*)(ws + alloc(256));
  int*   list   = (int*)(ws + alloc((size_t)E_ * T_ * 4));
  __hip_bfloat16* eo   = (__hip_bfloat16*)(ws + alloc((size_t)T_ * 2 * HD_ * 2));
  __hip_bfloat16* comb = (__hip_bfloat16*)(ws + alloc((size_t)M8_ * D_ * 2));

  hipMemsetAsync(cnt, 0, 256, stream);
  cvt_bf16_k<<<8192, 256, 0, stream>>>(x, xb);
  tcvt<<<dim3(32, 32, 1), 256, 0, stream>>>(Wm, WmT, 1024, 1024);
  tcvt<<<dim3(32, 32, 1), 256, 0, stream>>>(Wo, WoT, 1024, 1024);
  tcvt<<<dim3(16, 4, 16), 256, 0, stream>>>(W1, W1T, 128, 512);
  tcvt<<<dim3(4, 16, 16), 256, 0, stream>>>(W2, W2T, 512, 128);
  build_wre<<<1024, 128, 0, stream>>>(Wm, bm, emb, Wre, rbias);
  gemm_bt<0><<<512, 256, 0, stream>>>(xb, WmT, bm, hb, M8_, D_, D_);
  route_gemm<<<256, 256, 0, stream>>>(x, Wre, rbias, logits);
  route_topk<<<256, 256, 0, stream>>>(logits, topw, list, cnt);
  expert_mlp<<<16384, 256, 0, stream>>>(hb, W1T, W2T, b1, b2, topw, list, cnt, eo);
  combine_k<<<4096, 256, 0, stream>>>(eo, comb);
  gemm_bt<1><<<512, 256, 0, stream>>>(comb, WoT, bo, d_out, M8_, D_, D_);
}

// Round 3
// 596.158 us; speedup vs baseline: 1.7509x; 1.7509x over previous
//
#include <hip/hip_runtime.h>
#include <hip/hip_bf16.h>

typedef __attribute__((ext_vector_type(8))) short bx8;
typedef __attribute__((ext_vector_type(4))) short sx4;
typedef __attribute__((ext_vector_type(4))) float fx4;

#define D_   1024
#define H_   8
#define E_   16
#define HD_  128
#define I_   512
#define M8_  8192      // BS*L
#define T_   65536     // M8*H

__device__ inline float bf2f(short u) {
  unsigned int x = ((unsigned int)(unsigned short)u) << 16;
  return __builtin_bit_cast(float, x);
}
__device__ inline short f2bf(float f) {
  __hip_bfloat16 h = __float2bfloat16(f);
  return __builtin_bit_cast(short, h);
}

__device__ inline void gload_lds16(const void* g, void* l) {
  __builtin_amdgcn_global_load_lds(
      (const __attribute__((address_space(1))) void*)g,
      (__attribute__((address_space(3))) void*)l, 16, 0, 0);
}

__device__ inline fx4 mfma16(bx8 a, bx8 b, fx4 c) {
  return __builtin_amdgcn_mfma_f32_16x16x32_bf16(a, b, c, 0, 0, 0);
}

// ---------------- conversions ----------------

__global__ __launch_bounds__(256) void cvt_bf16_k(const float* __restrict__ src,
                                                  __hip_bfloat16* __restrict__ dst) {
  int i = blockIdx.x * 256 + threadIdx.x;
  float4 v = *(const float4*)&src[(size_t)i * 4];
  sx4 o;
  o[0] = f2bf(v.x); o[1] = f2bf(v.y); o[2] = f2bf(v.z); o[3] = f2bf(v.w);
  *(sx4*)((short*)dst + (size_t)i * 4) = o;
}

// batched transpose+convert: dst[b][c][r] = src[b][r][c]
__global__ __launch_bounds__(256) void tcvt(const float* __restrict__ src,
                                            __hip_bfloat16* __restrict__ dst,
                                            int R, int C) {
  __shared__ float tile[32][33];
  int tx = threadIdx.x & 31, ty = threadIdx.x >> 5;
  int r0 = blockIdx.y * 32, c0 = blockIdx.x * 32;
  const float* s = src + (size_t)blockIdx.z * R * C;
  __hip_bfloat16* d = dst + (size_t)blockIdx.z * R * C;
#pragma unroll
  for (int i = ty; i < 32; i += 8) tile[i][tx] = s[(size_t)(r0 + i) * C + c0 + tx];
  __syncthreads();
#pragma unroll
  for (int i = ty; i < 32; i += 8)
    d[(size_t)(c0 + i) * R + r0 + tx] = __float2bfloat16(tile[tx][i]);
}

// W2R[e][c][o][k] = W2[e][c*64+k][o]  (chunk-major bf16 layout for expert GEMM2 staging)
__global__ __launch_bounds__(256) void build_w2r(const float* __restrict__ W2,
                                                 __hip_bfloat16* __restrict__ W2R) {
  __shared__ float t[64][65];
  int e = blockIdx.z, c = blockIdx.y, og = blockIdx.x;
  int o = threadIdx.x & 63, kq = threadIdx.x >> 6;
  const float* src = W2 + ((size_t)e * 512 + c * 64) * 128 + og * 64;
#pragma unroll
  for (int kk = 0; kk < 16; ++kk) {
    int k = kq * 16 + kk;
    t[k][o] = src[(size_t)k * 128 + o];
  }
  __syncthreads();
  int k2 = threadIdx.x & 63, oq = threadIdx.x >> 6;
  __hip_bfloat16* dst = W2R + (((size_t)e * 8 + c) * 128 + og * 64) * 64;
#pragma unroll
  for (int oo = 0; oo < 16; ++oo) {
    int o2 = oq * 16 + oo;
    dst[(size_t)o2 * 64 + k2] = __float2bfloat16(t[k2][o2]);
  }
}

// ---------------- routing (exact fp32 path) ----------------

__global__ __launch_bounds__(128) void build_wre(const float* __restrict__ Wm,
                                                 const float* __restrict__ bm,
                                                 const float* __restrict__ emb,
                                                 float* __restrict__ Wre,
                                                 float* __restrict__ rbias) {
  __shared__ float wrow[1024];
  __shared__ float embs[2048];
  int tid = threadIdx.x;
  int d = blockIdx.x;
  for (int i = tid; i < 2048; i += 128) embs[i] = emb[i];
  for (int i = tid; i < 1024; i += 128) wrow[i] = Wm[(size_t)d * 1024 + i];
  __syncthreads();
  int eta = tid >> 4, e = tid & 15;
  float acc = 0.f;
  for (int c = 0; c < 128; ++c) acc = fmaf(wrow[eta * 128 + c], embs[c * 16 + e], acc);
  Wre[(size_t)d * 128 + tid] = acc;
  if (blockIdx.x == 0) {
    float b = 0.f;
    for (int c = 0; c < 128; ++c) b = fmaf(bm[eta * 128 + c], embs[c * 16 + e], b);
    rbias[tid] = b;
  }
}

__global__ __launch_bounds__(256) void route_gemm(const float* __restrict__ x,
                                                  const float* __restrict__ Wre,
                                                  const float* __restrict__ rbias,
                                                  float* __restrict__ logits) {
  __shared__ float xs[32][128];
  int tid = threadIdx.x;
  int n = tid & 127, half = tid >> 7;
  int row0 = blockIdx.x * 32;
  float acc[16];
#pragma unroll
  for (int i = 0; i < 16; ++i) acc[i] = 0.f;
  for (int k0 = 0; k0 < 1024; k0 += 128) {
    __syncthreads();
#pragma unroll
    for (int j = 0; j < 4; ++j) {
      int i4 = tid * 4 + j * 1024;
      int row = i4 >> 7, col = i4 & 127;
      *(float4*)&xs[row][col] = *(const float4*)&x[(size_t)(row0 + row) * 1024 + k0 + col];
    }
    __syncthreads();
    for (int d4 = 0; d4 < 128; d4 += 4) {
      float w0 = Wre[(size_t)(k0 + d4 + 0) * 128 + n];
      float w1 = Wre[(size_t)(k0 + d4 + 1) * 128 + n];
      float w2 = Wre[(size_t)(k0 + d4 + 2) * 128 + n];
      float w3 = Wre[(size_t)(k0 + d4 + 3) * 128 + n];
#pragma unroll
      for (int i = 0; i < 16; ++i) {
        float4 xv = *(const float4*)&xs[half * 16 + i][d4];
        acc[i] = fmaf(xv.x, w0, acc[i]);
        acc[i] = fmaf(xv.y, w1, acc[i]);
        acc[i] = fmaf(xv.z, w2, acc[i]);
        acc[i] = fmaf(xv.w, w3, acc[i]);
      }
    }
  }
  float rb = rbias[n];
#pragma unroll
  for (int i = 0; i < 16; ++i)
    logits[(size_t)(row0 + half * 16 + i) * 128 + n] = acc[i] + rb;
}

// per sub-token softmax + top-2; hierarchical counting (LDS then one global atomic per expert)
__global__ __launch_bounds__(256) void route_topk(const float* __restrict__ logits,
                                                  float* __restrict__ topw,
                                                  int* __restrict__ list,
                                                  int* __restrict__ cnt) {
  __shared__ int lcnt[16];
  __shared__ int gbase[16];
  int tid = threadIdx.x;
  if (tid < 16) lcnt[tid] = 0;
  __syncthreads();
  int s = blockIdx.x * 256 + tid;
  const float* lp = logits + (size_t)(s >> 3) * 128 + (s & 7) * 16;
  float v[16];
#pragma unroll
  for (int j = 0; j < 4; ++j) {
    float4 t = *(const float4*)&lp[j * 4];
    v[j * 4 + 0] = t.x; v[j * 4 + 1] = t.y; v[j * 4 + 2] = t.z; v[j * 4 + 3] = t.w;
  }
  float v1 = -1e30f, v2 = -1e30f; int i1 = 0, i2 = 0;
#pragma unroll
  for (int e = 0; e < 16; ++e) {
    float val = v[e];
    if (val > v1) { v2 = v1; i2 = i1; v1 = val; i1 = e; }
    else if (val > v2) { v2 = val; i2 = e; }
  }
  float sum = 0.f;
#pragma unroll
  for (int e = 0; e < 16; ++e) sum += expf(v[e] - v1);
  topw[(size_t)2 * s + 0] = 1.0f / sum;
  topw[(size_t)2 * s + 1] = expf(v2 - v1) / sum;
  int lp1 = atomicAdd(&lcnt[i1], 1);
  int lp2 = atomicAdd(&lcnt[i2], 1);
  __syncthreads();
  if (tid < 16) gbase[tid] = atomicAdd(&cnt[tid], lcnt[tid]);
  __syncthreads();
  list[(size_t)i1 * T_ + gbase[i1] + lp1] = 2 * s;
  list[(size_t)i2 * T_ + gbase[i2] + lp2] = 2 * s + 1;
}

// ---------------- bf16 MFMA GEMM: C = A @ BT^T (+bias), BT is [N][K] ----------------

template <int OUTF32>
__global__ __launch_bounds__(256) void gemm_bt(const __hip_bfloat16* __restrict__ A,
                                               const __hip_bfloat16* __restrict__ BT,
                                               const float* __restrict__ bias,
                                               void* __restrict__ Cout,
                                               int M, int N, int Kd) {
  __shared__ __hip_bfloat16 As[128 * 64];
  __shared__ __hip_bfloat16 Bs[128 * 64];
  int tid = threadIdx.x;
  int lane = tid & 63, w = tid >> 6;
  int nbn = N >> 7;
  int bm = blockIdx.x / nbn, bn = blockIdx.x % nbn;
  int wm = w >> 1, wn = w & 1;
  int r = lane & 15, g = lane >> 4;
  const fx4 fz = {0.f, 0.f, 0.f, 0.f};
  fx4 acc[4][4];
#pragma unroll
  for (int m = 0; m < 4; ++m)
#pragma unroll
    for (int n = 0; n < 4; ++n) acc[m][n] = fz;
  const short* AsS = (const short*)As;
  const short* BsS = (const short*)Bs;
  for (int k0 = 0; k0 < Kd; k0 += 64) {
    __syncthreads();
#pragma unroll
    for (int i = 0; i < 4; ++i) {
      int c = i * 256 + w * 64 + lane;
      int row = c >> 3, ko = (c & 7) * 8;
      gload_lds16(A + (size_t)(bm * 128 + row) * Kd + k0 + ko,
                  (void*)(As + (size_t)(i * 256 + w * 64) * 8));
    }
#pragma unroll
    for (int i = 0; i < 4; ++i) {
      int c = i * 256 + w * 64 + lane;
      int row = c >> 3, ko = (c & 7) * 8;
      gload_lds16(BT + (size_t)(bn * 128 + row) * Kd + k0 + ko,
                  (void*)(Bs + (size_t)(i * 256 + w * 64) * 8));
    }
    __syncthreads();
#pragma unroll
    for (int kb = 0; kb < 2; ++kb) {
      bx8 af[4], bfr[4];
#pragma unroll
      for (int m = 0; m < 4; ++m)
        af[m] = *(const bx8*)(AsS + (wm * 64 + m * 16 + r) * 64 + kb * 32 + g * 8);
#pragma unroll
      for (int n = 0; n < 4; ++n)
        bfr[n] = *(const bx8*)(BsS + (wn * 64 + n * 16 + r) * 64 + kb * 32 + g * 8);
#pragma unroll
      for (int m = 0; m < 4; ++m)
#pragma unroll
        for (int n = 0; n < 4; ++n)
          acc[m][n] = mfma16(af[m], bfr[n], acc[m][n]);
    }
  }
#pragma unroll
  for (int n = 0; n < 4; ++n) {
    int col = bn * 128 + wn * 64 + n * 16 + r;
    float bv = bias[col];
#pragma unroll
    for (int m = 0; m < 4; ++m) {
      int rowb = bm * 128 + wm * 64 + m * 16 + g * 4;
#pragma unroll
      for (int ri = 0; ri < 4; ++ri) {
        float val = acc[m][n][ri] + bv;
        if (OUTF32) ((float*)Cout)[(size_t)(rowb + ri) * N + col] = val;
        else ((__hip_bfloat16*)Cout)[(size_t)(rowb + ri) * N + col] = __float2bfloat16(val);
      }
    }
  }
}

// ---------------- fused per-expert MLP v2 ----------------
// 128 rows/block, 4 waves x 32 rows. A-frags in registers (loaded once).
// W1/W2 chunks staged to LDS via global_load_lds with inverse-swizzle-on-source;
// reads use matching XOR swizzle. Hc (hmid chunk) wave-private LDS roundtrip.

__global__ __launch_bounds__(256) void expert_mlp2(const __hip_bfloat16* __restrict__ h,
                                                   const __hip_bfloat16* __restrict__ W1T,
                                                   const __hip_bfloat16* __restrict__ W2R,
                                                   const float* __restrict__ b1,
                                                   const float* __restrict__ b2,
                                                   const float* __restrict__ topw,
                                                   const int* __restrict__ list,
                                                   const int* __restrict__ cnt,
                                                   __hip_bfloat16* __restrict__ eo) {
  int e = blockIdx.x >> 9, tile = blockIdx.x & 511;
  int cnt_e = cnt[e];
  int base = tile * 128;
  if (base >= cnt_e) return;
  __shared__ short W1c[64 * 128];   // 16KB: [n-row 64][k 128], 16B-unit swizzled
  __shared__ short W2c[128 * 64];   // 16KB: [out-row 128][k 64], swizzled
  __shared__ short Hc[128 * 64];    // 16KB: [row 128][i-col 64], swizzled
  __shared__ int pids[128];
  __shared__ float wrow[128];
  int tid = threadIdx.x, lane = tid & 63, wv = tid >> 6;
  int r = lane & 15, g = lane >> 4;
  if (tid < 128) {
    int idx = base + tid;
    int p = (idx < cnt_e) ? list[(size_t)e * T_ + idx] : -1;
    pids[tid] = p;
    wrow[tid] = (p >= 0) ? topw[p] : 0.f;
  }
  __syncthreads();

  // A fragments in registers: rows wv*32 + m*16 + r, all K=128
  const short* hS = (const short*)h;
  bx8 af[2][4];
#pragma unroll
  for (int m = 0; m < 2; ++m) {
    int row = wv * 32 + m * 16 + r;
    int p = pids[row];
    size_t st = (p >= 0) ? (size_t)(p >> 1) : 0;
    const short* rp = hS + st * 128 + g * 8;
#pragma unroll
    for (int kb = 0; kb < 4; ++kb) af[m][kb] = *(const bx8*)(rp + kb * 32);
  }

  const char* W1S = (const char*)(W1T + (size_t)e * I_ * HD_);
  const float* b1e = b1 + (size_t)e * I_;
  const float* b2e = b2 + (size_t)e * HD_;
  const fx4 fz = {0.f, 0.f, 0.f, 0.f};
  fx4 acc2[2][8];
#pragma unroll
  for (int m = 0; m < 2; ++m)
#pragma unroll
    for (int n = 0; n < 8; ++n) acc2[m][n] = fz;

  for (int c = 0; c < 8; ++c) {
    __syncthreads();
    // stage W1 chunk: rows c*64..c*64+64 of W1T[e] (256B rows, 16 units)
#pragma unroll
    for (int j = 0; j < 4; ++j) {
      int row = wv * 16 + j * 4 + (lane >> 4);
      int o = lane & 15;
      int grow = c * 64 + row;
      gload_lds16(W1S + (size_t)grow * 256 + ((o * 16) ^ ((row & 7) << 4)),
                  (char*)W1c + (wv * 16 + j * 4) * 256);
    }
    // stage W2 chunk: W2R[e][c] = [128 out][64 k] contiguous (128B rows, 8 units)
    const char* W2S = (const char*)(W2R + (((size_t)e * 8 + c) * 128) * 64);
#pragma unroll
    for (int j = 0; j < 4; ++j) {
      int row = wv * 32 + j * 8 + (lane >> 3);
      int o = lane & 7;
      gload_lds16(W2S + (size_t)row * 128 + ((o * 16) ^ ((row & 7) << 4)),
                  (char*)W2c + (wv * 32 + j * 8) * 128);
    }
    __syncthreads();

    // GEMM1: [32 rows x 64 cols] per wave, K=128
    fx4 acc1[2][4];
#pragma unroll
    for (int m = 0; m < 2; ++m)
#pragma unroll
      for (int n = 0; n < 4; ++n) acc1[m][n] = fz;
#pragma unroll
    for (int kb = 0; kb < 4; ++kb) {
      bx8 bf[4];
#pragma unroll
      for (int n = 0; n < 4; ++n) {
        int brow = n * 16 + r;
        bf[n] = *(const bx8*)((const char*)W1c + brow * 256 +
                              ((kb * 64 + g * 16) ^ ((brow & 7) << 4)));
      }
#pragma unroll
      for (int m = 0; m < 2; ++m)
#pragma unroll
        for (int n = 0; n < 4; ++n) acc1[m][n] = mfma16(af[m][kb], bf[n], acc1[m][n]);
    }

    // GELU (exact erf) -> Hc (wave-private rows)
#pragma unroll
    for (int m = 0; m < 2; ++m)
#pragma unroll
      for (int n = 0; n < 4; ++n) {
        int col = n * 16 + r;
        float b1v = b1e[c * 64 + col];
#pragma unroll
        for (int ri = 0; ri < 4; ++ri) {
          int row = wv * 32 + m * 16 + g * 4 + ri;
          float xg = acc1[m][n][ri] + b1v;
          float ge = 0.5f * xg * (1.f + erff(xg * 0.70710678118f));
          *(short*)((char*)Hc + row * 128 + ((col * 2) ^ ((row & 7) << 4))) = f2bf(ge);
        }
      }

    // GEMM2 partial: [32 rows x 128 out] per wave, k-slice 64
#pragma unroll
    for (int kb2 = 0; kb2 < 2; ++kb2) {
      bx8 ha[2];
#pragma unroll
      for (int m = 0; m < 2; ++m) {
        int row = wv * 32 + m * 16 + r;
        ha[m] = *(const bx8*)((const char*)Hc + row * 128 +
                              ((kb2 * 64 + g * 16) ^ ((row & 7) << 4)));
      }
#pragma unroll
      for (int n = 0; n < 8; ++n) {
        int brow = n * 16 + r;
        bx8 wb = *(const bx8*)((const char*)W2c + brow * 128 +
                               ((kb2 * 64 + g * 16) ^ ((brow & 7) << 4)));
#pragma unroll
        for (int m = 0; m < 2; ++m) acc2[m][n] = mfma16(ha[m], wb, acc2[m][n]);
      }
    }
  }

  // epilogue: bias, router weight, scatter
#pragma unroll
  for (int n = 0; n < 8; ++n) {
    int col = n * 16 + r;
    float b2v = b2e[col];
#pragma unroll
    for (int m = 0; m < 2; ++m)
#pragma unroll
      for (int ri = 0; ri < 4; ++ri) {
        int row = wv * 32 + m * 16 + g * 4 + ri;
        int p = pids[row];
        if (p >= 0) {
          float v = (acc2[m][n][ri] + b2v) * wrow[row];
          eo[(size_t)p * 128 + col] = __float2bfloat16(v);
        }
      }
  }
}

// comb[s][:] = eo[2s][:] + eo[2s+1][:]   (weights already applied)
__global__ __launch_bounds__(256) void combine_k(const __hip_bfloat16* __restrict__ eo,
                                                 __hip_bfloat16* __restrict__ comb) {
  int t = blockIdx.x * 256 + threadIdx.x;
  int s = t >> 4, oo = (t & 15) * 8;
  const short* eS = (const short*)eo;
  bx8 a = *(const bx8*)(eS + (size_t)s * 256 + oo);
  bx8 b = *(const bx8*)(eS + (size_t)s * 256 + 128 + oo);
  bx8 ov;
#pragma unroll
  for (int j = 0; j < 8; ++j) ov[j] = f2bf(bf2f(a[j]) + bf2f(b[j]));
  *(bx8*)((short*)comb + (size_t)s * 128 + oo) = ov;
}

// ---------------- host ----------------

extern "C" void kernel_launch(void* const* d_in, const int* in_sizes, int n_in,
                              void* d_out, int out_size, void* d_ws, size_t ws_size,
                              hipStream_t stream) {
  const float* x   = (const float*)d_in[0];
  const float* Wm  = (const float*)d_in[1];
  const float* bm  = (const float*)d_in[2];
  const float* emb = (const float*)d_in[3];
  const float* W1  = (const float*)d_in[4];
  const float* b1  = (const float*)d_in[5];
  const float* W2  = (const float*)d_in[6];
  const float* b2  = (const float*)d_in[7];
  const float* Wo  = (const float*)d_in[8];
  const float* bo  = (const float*)d_in[9];

  char* ws = (char*)d_ws;
  size_t off = 0;
  auto alloc = [&](size_t b) { size_t r = off; off += (b + 255) & ~(size_t)255; return r; };
  __hip_bfloat16* xb   = (__hip_bfloat16*)(ws + alloc((size_t)M8_ * D_ * 2));
  __hip_bfloat16* WmT  = (__hip_bfloat16*)(ws + alloc((size_t)D_ * D_ * 2));
  __hip_bfloat16* WoT  = (__hip_bfloat16*)(ws + alloc((size_t)D_ * D_ * 2));
  __hip_bfloat16* W1T  = (__hip_bfloat16*)(ws + alloc((size_t)E_ * HD_ * I_ * 2));
  __hip_bfloat16* W2R  = (__hip_bfloat16*)(ws + alloc((size_t)E_ * HD_ * I_ * 2));
  __hip_bfloat16* hb   = (__hip_bfloat16*)(ws + alloc((size_t)M8_ * D_ * 2));
  float* Wre    = (float*)(ws + alloc((size_t)D_ * 128 * 4));
  float* rbias  = (float*)(ws + alloc(512));
  float* logits = (float*)(ws + alloc((size_t)T_ * 16 * 4));
  float* topw   = (float*)(ws + alloc((size_t)T_ * 2 * 4));
  int*   cnt    = (int*)(ws + alloc(256));
  int*   list   = (int*)(ws + alloc((size_t)E_ * T_ * 4));
  __hip_bfloat16* eo   = (__hip_bfloat16*)(ws + alloc((size_t)T_ * 2 * HD_ * 2));
  __hip_bfloat16* comb = (__hip_bfloat16*)(ws + alloc((size_t)M8_ * D_ * 2));

  hipMemsetAsync(cnt, 0, 256, stream);
  cvt_bf16_k<<<8192, 256, 0, stream>>>(x, xb);
  tcvt<<<dim3(32, 32, 1), 256, 0, stream>>>(Wm, WmT, 1024, 1024);
  tcvt<<<dim3(32, 32, 1), 256, 0, stream>>>(Wo, WoT, 1024, 1024);
  tcvt<<<dim3(16, 4, 16), 256, 0, stream>>>(W1, W1T, 128, 512);
  build_w2r<<<dim3(2, 8, 16), 256, 0, stream>>>(W2, W2R);
  build_wre<<<1024, 128, 0, stream>>>(Wm, bm, emb, Wre, rbias);
  gemm_bt<0><<<512, 256, 0, stream>>>(xb, WmT, bm, hb, M8_, D_, D_);
  route_gemm<<<256, 256, 0, stream>>>(x, Wre, rbias, logits);
  route_topk<<<256, 256, 0, stream>>>(logits, topw, list, cnt);
  expert_mlp2<<<8192, 256, 0, stream>>>(hb, W1T, W2R, b1, b2, topw, list, cnt, eo);
  combine_k<<<4096, 256, 0, stream>>>(eo, comb);
  gemm_bt<1><<<512, 256, 0, stream>>>(comb, WoT, bo, d_out, M8_, D_, D_);
}

// Round 4
// 405.695 us; speedup vs baseline: 2.5730x; 1.4695x over previous
//
#include <hip/hip_runtime.h>
#include <hip/hip_bf16.h>
#include <math.h>

typedef __attribute__((ext_vector_type(8))) short bx8;
typedef __attribute__((ext_vector_type(4))) short sx4;
typedef __attribute__((ext_vector_type(4))) float fx4;

#define D_   1024
#define H_   8
#define E_   16
#define HD_  128
#define I_   512
#define M8_  8192      // BS*L
#define T_   65536     // M8*H

__device__ inline float bf2f(short u) {
  unsigned int x = ((unsigned int)(unsigned short)u) << 16;
  return __builtin_bit_cast(float, x);
}
__device__ inline short f2bf(float f) {
  __hip_bfloat16 h = __float2bfloat16(f);
  return __builtin_bit_cast(short, h);
}

__device__ inline void gload_lds16(const void* g, void* l) {
  __builtin_amdgcn_global_load_lds(
      (const __attribute__((address_space(1))) void*)g,
      (__attribute__((address_space(3))) void*)l, 16, 0, 0);
}

__device__ inline fx4 mfma16(bx8 a, bx8 b, fx4 c) {
  return __builtin_amdgcn_mfma_f32_16x16x32_bf16(a, b, c, 0, 0, 0);
}

// exact-class GELU: erf via Abramowitz-Stegun 7.1.26 (abs err 1.5e-7, ~18 VALU ops)
__device__ inline float gelu_erf(float x) {
  float z = fabsf(x) * 0.70710678118654752f;
  float t = __builtin_amdgcn_rcpf(fmaf(0.3275911f, z, 1.f));
  float p = t * fmaf(t, fmaf(t, fmaf(t, fmaf(t, 1.061405429f, -1.453152027f),
                                     1.421413741f), -0.284496736f), 0.254829592f);
  float er = fmaf(-p, __expf(-z * z), 1.f);
  er = copysignf(er, x);
  return 0.5f * x * (1.f + er);
}

// ---------------- conversions ----------------

__global__ __launch_bounds__(256) void cvt_bf16_k(const float* __restrict__ src,
                                                  __hip_bfloat16* __restrict__ dst) {
  int i = blockIdx.x * 256 + threadIdx.x;
  float4 v = *(const float4*)&src[(size_t)i * 4];
  sx4 o;
  o[0] = f2bf(v.x); o[1] = f2bf(v.y); o[2] = f2bf(v.z); o[3] = f2bf(v.w);
  *(sx4*)((short*)dst + (size_t)i * 4) = o;
}

// batched transpose+convert: dst[b][c][r] = src[b][r][c]
__global__ __launch_bounds__(256) void tcvt(const float* __restrict__ src,
                                            __hip_bfloat16* __restrict__ dst,
                                            int R, int C) {
  __shared__ float tile[32][33];
  int tx = threadIdx.x & 31, ty = threadIdx.x >> 5;
  int r0 = blockIdx.y * 32, c0 = blockIdx.x * 32;
  const float* s = src + (size_t)blockIdx.z * R * C;
  __hip_bfloat16* d = dst + (size_t)blockIdx.z * R * C;
#pragma unroll
  for (int i = ty; i < 32; i += 8) tile[i][tx] = s[(size_t)(r0 + i) * C + c0 + tx];
  __syncthreads();
#pragma unroll
  for (int i = ty; i < 32; i += 8)
    d[(size_t)(c0 + i) * R + r0 + tx] = __float2bfloat16(tile[tx][i]);
}

// ---------------- routing (exact fp32 path) ----------------

__global__ __launch_bounds__(128) void build_wre(const float* __restrict__ Wm,
                                                 const float* __restrict__ bm,
                                                 const float* __restrict__ emb,
                                                 float* __restrict__ Wre,
                                                 float* __restrict__ rbias) {
  __shared__ float wrow[1024];
  __shared__ float embs[2048];
  int tid = threadIdx.x;
  int d = blockIdx.x;
  for (int i = tid; i < 2048; i += 128) embs[i] = emb[i];
  for (int i = tid; i < 1024; i += 128) wrow[i] = Wm[(size_t)d * 1024 + i];
  __syncthreads();
  int eta = tid >> 4, e = tid & 15;
  float acc = 0.f;
  for (int c = 0; c < 128; ++c) acc = fmaf(wrow[eta * 128 + c], embs[c * 16 + e], acc);
  Wre[(size_t)d * 128 + tid] = acc;
  if (blockIdx.x == 0) {
    float b = 0.f;
    for (int c = 0; c < 128; ++c) b = fmaf(bm[eta * 128 + c], embs[c * 16 + e], b);
    rbias[tid] = b;
  }
}

__global__ __launch_bounds__(256) void route_gemm(const float* __restrict__ x,
                                                  const float* __restrict__ Wre,
                                                  const float* __restrict__ rbias,
                                                  float* __restrict__ logits) {
  __shared__ float xs[32][128];
  int tid = threadIdx.x;
  int n = tid & 127, half = tid >> 7;
  int row0 = blockIdx.x * 32;
  float acc[16];
#pragma unroll
  for (int i = 0; i < 16; ++i) acc[i] = 0.f;
  for (int k0 = 0; k0 < 1024; k0 += 128) {
    __syncthreads();
#pragma unroll
    for (int j = 0; j < 4; ++j) {
      int i4 = tid * 4 + j * 1024;
      int row = i4 >> 7, col = i4 & 127;
      *(float4*)&xs[row][col] = *(const float4*)&x[(size_t)(row0 + row) * 1024 + k0 + col];
    }
    __syncthreads();
    for (int d4 = 0; d4 < 128; d4 += 4) {
      float w0 = Wre[(size_t)(k0 + d4 + 0) * 128 + n];
      float w1 = Wre[(size_t)(k0 + d4 + 1) * 128 + n];
      float w2 = Wre[(size_t)(k0 + d4 + 2) * 128 + n];
      float w3 = Wre[(size_t)(k0 + d4 + 3) * 128 + n];
#pragma unroll
      for (int i = 0; i < 16; ++i) {
        float4 xv = *(const float4*)&xs[half * 16 + i][d4];
        acc[i] = fmaf(xv.x, w0, acc[i]);
        acc[i] = fmaf(xv.y, w1, acc[i]);
        acc[i] = fmaf(xv.z, w2, acc[i]);
        acc[i] = fmaf(xv.w, w3, acc[i]);
      }
    }
  }
  float rb = rbias[n];
#pragma unroll
  for (int i = 0; i < 16; ++i)
    logits[(size_t)(row0 + half * 16 + i) * 128 + n] = acc[i] + rb;
}

// per sub-token softmax + top-2; hierarchical counting
__global__ __launch_bounds__(256) void route_topk(const float* __restrict__ logits,
                                                  float* __restrict__ topw,
                                                  int* __restrict__ list,
                                                  int* __restrict__ cnt) {
  __shared__ int lcnt[16];
  __shared__ int gbase[16];
  int tid = threadIdx.x;
  if (tid < 16) lcnt[tid] = 0;
  __syncthreads();
  int s = blockIdx.x * 256 + tid;
  const float* lp = logits + (size_t)(s >> 3) * 128 + (s & 7) * 16;
  float v[16];
#pragma unroll
  for (int j = 0; j < 4; ++j) {
    float4 t = *(const float4*)&lp[j * 4];
    v[j * 4 + 0] = t.x; v[j * 4 + 1] = t.y; v[j * 4 + 2] = t.z; v[j * 4 + 3] = t.w;
  }
  float v1 = -1e30f, v2 = -1e30f; int i1 = 0, i2 = 0;
#pragma unroll
  for (int e = 0; e < 16; ++e) {
    float val = v[e];
    if (val > v1) { v2 = v1; i2 = i1; v1 = val; i1 = e; }
    else if (val > v2) { v2 = val; i2 = e; }
  }
  float sum = 0.f;
#pragma unroll
  for (int e = 0; e < 16; ++e) sum += expf(v[e] - v1);
  topw[(size_t)2 * s + 0] = 1.0f / sum;
  topw[(size_t)2 * s + 1] = expf(v2 - v1) / sum;
  int lp1 = atomicAdd(&lcnt[i1], 1);
  int lp2 = atomicAdd(&lcnt[i2], 1);
  __syncthreads();
  if (tid < 16) gbase[tid] = atomicAdd(&cnt[tid], lcnt[tid]);
  __syncthreads();
  list[(size_t)i1 * T_ + gbase[i1] + lp1] = 2 * s;
  list[(size_t)i2 * T_ + gbase[i2] + lp2] = 2 * s + 1;
}

// 64-row tile bases per expert (exclusive prefix over ceil(cnt/64))
__global__ void prefix_k(const int* __restrict__ cnt, int* __restrict__ tileBase) {
  if (threadIdx.x == 0 && blockIdx.x == 0) {
    int s = 0;
#pragma unroll
    for (int e = 0; e < 16; ++e) { tileBase[e] = s; s += (cnt[e] + 63) >> 6; }
    tileBase[16] = s;
  }
}

// ---------------- bf16 MFMA GEMM: C = A @ BT^T (+bias), BT is [N][K] ----------------

template <int OUTF32>
__global__ __launch_bounds__(256) void gemm_bt(const __hip_bfloat16* __restrict__ A,
                                               const __hip_bfloat16* __restrict__ BT,
                                               const float* __restrict__ bias,
                                               void* __restrict__ Cout,
                                               int M, int N, int Kd) {
  __shared__ __hip_bfloat16 As[128 * 64];
  __shared__ __hip_bfloat16 Bs[128 * 64];
  int tid = threadIdx.x;
  int lane = tid & 63, w = tid >> 6;
  int nbn = N >> 7;
  // XCD-aware swizzle (gridDim divisible by 8)
  int cpx = gridDim.x >> 3;
  int swz = (blockIdx.x & 7) * cpx + (blockIdx.x >> 3);
  int bm = swz / nbn, bn = swz % nbn;
  int wm = w >> 1, wn = w & 1;
  int r = lane & 15, g = lane >> 4;
  const fx4 fz = {0.f, 0.f, 0.f, 0.f};
  fx4 acc[4][4];
#pragma unroll
  for (int m = 0; m < 4; ++m)
#pragma unroll
    for (int n = 0; n < 4; ++n) acc[m][n] = fz;
  const short* AsS = (const short*)As;
  const short* BsS = (const short*)Bs;
  for (int k0 = 0; k0 < Kd; k0 += 64) {
    __syncthreads();
#pragma unroll
    for (int i = 0; i < 4; ++i) {
      int c = i * 256 + w * 64 + lane;
      int row = c >> 3, ko = (c & 7) * 8;
      gload_lds16(A + (size_t)(bm * 128 + row) * Kd + k0 + ko,
                  (void*)(As + (size_t)(i * 256 + w * 64) * 8));
    }
#pragma unroll
    for (int i = 0; i < 4; ++i) {
      int c = i * 256 + w * 64 + lane;
      int row = c >> 3, ko = (c & 7) * 8;
      gload_lds16(BT + (size_t)(bn * 128 + row) * Kd + k0 + ko,
                  (void*)(Bs + (size_t)(i * 256 + w * 64) * 8));
    }
    __syncthreads();
#pragma unroll
    for (int kb = 0; kb < 2; ++kb) {
      bx8 af[4], bfr[4];
#pragma unroll
      for (int m = 0; m < 4; ++m)
        af[m] = *(const bx8*)(AsS + (wm * 64 + m * 16 + r) * 64 + kb * 32 + g * 8);
#pragma unroll
      for (int n = 0; n < 4; ++n)
        bfr[n] = *(const bx8*)(BsS + (wn * 64 + n * 16 + r) * 64 + kb * 32 + g * 8);
#pragma unroll
      for (int m = 0; m < 4; ++m)
#pragma unroll
        for (int n = 0; n < 4; ++n)
          acc[m][n] = mfma16(af[m], bfr[n], acc[m][n]);
    }
  }
#pragma unroll
  for (int n = 0; n < 4; ++n) {
    int col = bn * 128 + wn * 64 + n * 16 + r;
    float bv = bias[col];
#pragma unroll
    for (int m = 0; m < 4; ++m) {
      int rowb = bm * 128 + wm * 64 + m * 16 + g * 4;
#pragma unroll
      for (int ri = 0; ri < 4; ++ri) {
        float val = acc[m][n][ri] + bv;
        if (OUTF32) ((float*)Cout)[(size_t)(rowb + ri) * N + col] = val;
        else ((__hip_bfloat16*)Cout)[(size_t)(rowb + ri) * N + col] = __float2bfloat16(val);
      }
    }
  }
}

// ---------------- fused per-expert MLP v3 ----------------
// 64 rows/block, 4 waves x 16 rows. Exact tiling via tileBase (no dud blocks).
// LDS exactly 40KiB -> 4 blocks/CU. Swapped GEMM1 (mfma(W1,token)) so hmid
// lands token-major -> vectorized Hc roundtrip (b64 writes / b128 reads).

__global__ __launch_bounds__(256, 4) void expert_mlp3(
    const __hip_bfloat16* __restrict__ h,
    const __hip_bfloat16* __restrict__ W1T,   // [E][512 i][128 d]
    const __hip_bfloat16* __restrict__ W2T,   // [E][128 o][512 i]
    const float* __restrict__ b1,
    const float* __restrict__ b2,
    const float* __restrict__ topw,
    const int* __restrict__ list,
    const int* __restrict__ cnt,
    const int* __restrict__ tileBase,
    __hip_bfloat16* __restrict__ eo) {
  int b = blockIdx.x;
  if (b >= tileBase[16]) return;
  int e = 0;
#pragma unroll
  for (int i = 1; i < 16; ++i) e += (b >= tileBase[i]);
  int tile = b - tileBase[e];
  int cnt_e = cnt[e];
  int base = tile * 64;
  if (base >= cnt_e) return;

  __shared__ short W1c[64 * 128];   // 16 KiB: [64 i][128 d], 16B-unit swizzled
  __shared__ short W2c[128 * 64];   // 16 KiB: [128 o][64 i], swizzled
  __shared__ short Hc[4 * 16 * 64]; //  8 KiB: per-wave [16 t][64 i], swizzled

  int tid = threadIdx.x, lane = tid & 63, wv = tid >> 6;
  int r = lane & 15, g = lane >> 4;
  const int* liste = list + (size_t)e * T_;

  // own-token pid + B-fragments (token data) in registers
  int idx_own = base + wv * 16 + r;
  int p_own = (idx_own < cnt_e) ? liste[idx_own] : -1;
  const short* hS = (const short*)h;
  size_t st = (p_own >= 0) ? (size_t)(p_own >> 1) : 0;
  const short* rp = hS + st * 128 + g * 8;
  bx8 af[4];
#pragma unroll
  for (int kb = 0; kb < 4; ++kb) af[kb] = *(const bx8*)(rp + kb * 32);

  const char* W1S = (const char*)(W1T + (size_t)e * I_ * HD_);
  const char* W2S = (const char*)(W2T + (size_t)e * HD_ * I_);
  const float* b1e = b1 + (size_t)e * I_;
  const float* b2e = b2 + (size_t)e * HD_;
  char* HcW = (char*)Hc + wv * 16 * 128;

  const fx4 fz = {0.f, 0.f, 0.f, 0.f};
  fx4 acc2[8];
#pragma unroll
  for (int n = 0; n < 8; ++n) acc2[n] = fz;

  for (int c = 0; c < 8; ++c) {
    __syncthreads();
    // stage W1 chunk [64 i][128 d] (256B rows, 16 units)
#pragma unroll
    for (int j = 0; j < 4; ++j) {
      int row = wv * 16 + j * 4 + (lane >> 4);
      int u = lane & 15;
      gload_lds16(W1S + (size_t)(c * 64 + row) * 256 + ((u * 16) ^ ((row & 7) << 4)),
                  (char*)W1c + (wv * 16 + j * 4) * 256);
    }
    // stage W2 chunk [128 o][64 i] (128B row-slices of 1024B rows, 8 units)
#pragma unroll
    for (int j = 0; j < 4; ++j) {
      int row = wv * 32 + j * 8 + (lane >> 3);
      int u = lane & 7;
      gload_lds16(W2S + (size_t)row * 1024 + c * 128 + ((u * 16) ^ ((row & 7) << 4)),
                  (char*)W2c + (wv * 32 + j * 8) * 128);
    }
    __syncthreads();

    // GEMM1 (swapped): D1[i][t] = sum_d W1T[i][d] * h[t][d]
    fx4 acc1[4];
#pragma unroll
    for (int ib = 0; ib < 4; ++ib) acc1[ib] = fz;
#pragma unroll
    for (int kb = 0; kb < 4; ++kb) {
#pragma unroll
      for (int ib = 0; ib < 4; ++ib) {
        int irow = ib * 16 + r;
        bx8 a = *(const bx8*)((const char*)W1c + irow * 256 +
                              ((kb * 64 + g * 16) ^ ((irow & 7) << 4)));
        acc1[ib] = mfma16(a, af[kb], acc1[ib]);
      }
    }

    // GELU + vectorized Hc write: lane holds hmid[t=r][i = ib*16+g*4+ri]
#pragma unroll
    for (int ib = 0; ib < 4; ++ib) {
      float4 b1v = *(const float4*)&b1e[c * 64 + ib * 16 + g * 4];
      sx4 ov;
      ov[0] = f2bf(gelu_erf(acc1[ib][0] + b1v.x));
      ov[1] = f2bf(gelu_erf(acc1[ib][1] + b1v.y));
      ov[2] = f2bf(gelu_erf(acc1[ib][2] + b1v.z));
      ov[3] = f2bf(gelu_erf(acc1[ib][3] + b1v.w));
      *(sx4*)(HcW + r * 128 + ((ib * 32 + g * 8) ^ ((r & 7) << 4))) = ov;
    }

    // GEMM2 partial: D2[t][o] += sum_{i in chunk} hmid[t][i] * W2T[o][i]
#pragma unroll
    for (int kb2 = 0; kb2 < 2; ++kb2) {
      bx8 ha = *(const bx8*)(HcW + r * 128 + ((kb2 * 64 + g * 16) ^ ((r & 7) << 4)));
#pragma unroll
      for (int ob = 0; ob < 8; ++ob) {
        int orow = ob * 16 + r;
        bx8 wb = *(const bx8*)((const char*)W2c + orow * 128 +
                               ((kb2 * 64 + g * 16) ^ ((orow & 7) << 4)));
        acc2[ob] = mfma16(ha, wb, acc2[ob]);
      }
    }
  }

  // epilogue: acc2[ob][ri] = eo[t = g*4+ri][o = ob*16+r]
  int pid_ep[4];
  float wt_ep[4];
#pragma unroll
  for (int ri = 0; ri < 4; ++ri) {
    int idx = base + wv * 16 + g * 4 + ri;
    int p = (idx < cnt_e) ? liste[idx] : -1;
    pid_ep[ri] = p;
    wt_ep[ri] = (p >= 0) ? topw[p] : 0.f;
  }
#pragma unroll
  for (int ob = 0; ob < 8; ++ob) {
    float b2v = b2e[ob * 16 + r];
#pragma unroll
    for (int ri = 0; ri < 4; ++ri) {
      int p = pid_ep[ri];
      if (p >= 0) {
        float v = (acc2[ob][ri] + b2v) * wt_ep[ri];
        eo[(size_t)p * 128 + ob * 16 + r] = __float2bfloat16(v);
      }
    }
  }
}

// comb[s][:] = eo[2s][:] + eo[2s+1][:]   (weights already applied)
__global__ __launch_bounds__(256) void combine_k(const __hip_bfloat16* __restrict__ eo,
                                                 __hip_bfloat16* __restrict__ comb) {
  int t = blockIdx.x * 256 + threadIdx.x;
  int s = t >> 4, oo = (t & 15) * 8;
  const short* eS = (const short*)eo;
  bx8 a = *(const bx8*)(eS + (size_t)s * 256 + oo);
  bx8 b = *(const bx8*)(eS + (size_t)s * 256 + 128 + oo);
  bx8 ov;
#pragma unroll
  for (int j = 0; j < 8; ++j) ov[j] = f2bf(bf2f(a[j]) + bf2f(b[j]));
  *(bx8*)((short*)comb + (size_t)s * 128 + oo) = ov;
}

// ---------------- host ----------------

extern "C" void kernel_launch(void* const* d_in, const int* in_sizes, int n_in,
                              void* d_out, int out_size, void* d_ws, size_t ws_size,
                              hipStream_t stream) {
  const float* x   = (const float*)d_in[0];
  const float* Wm  = (const float*)d_in[1];
  const float* bm  = (const float*)d_in[2];
  const float* emb = (const float*)d_in[3];
  const float* W1  = (const float*)d_in[4];
  const float* b1  = (const float*)d_in[5];
  const float* W2  = (const float*)d_in[6];
  const float* b2  = (const float*)d_in[7];
  const float* Wo  = (const float*)d_in[8];
  const float* bo  = (const float*)d_in[9];

  char* ws = (char*)d_ws;
  size_t off = 0;
  auto alloc = [&](size_t b) { size_t r = off; off += (b + 255) & ~(size_t)255; return r; };
  __hip_bfloat16* xb   = (__hip_bfloat16*)(ws + alloc((size_t)M8_ * D_ * 2));
  __hip_bfloat16* WmT  = (__hip_bfloat16*)(ws + alloc((size_t)D_ * D_ * 2));
  __hip_bfloat16* WoT  = (__hip_bfloat16*)(ws + alloc((size_t)D_ * D_ * 2));
  __hip_bfloat16* W1T  = (__hip_bfloat16*)(ws + alloc((size_t)E_ * HD_ * I_ * 2));
  __hip_bfloat16* W2T  = (__hip_bfloat16*)(ws + alloc((size_t)E_ * HD_ * I_ * 2));
  __hip_bfloat16* hb   = (__hip_bfloat16*)(ws + alloc((size_t)M8_ * D_ * 2));
  float* Wre    = (float*)(ws + alloc((size_t)D_ * 128 * 4));
  float* rbias  = (float*)(ws + alloc(512));
  float* logits = (float*)(ws + alloc((size_t)T_ * 16 * 4));
  float* topw   = (float*)(ws + alloc((size_t)T_ * 2 * 4));
  int*   cnt    = (int*)(ws + alloc(256));
  int*   tileBase = (int*)(ws + alloc(256));
  int*   list   = (int*)(ws + alloc((size_t)E_ * T_ * 4));
  __hip_bfloat16* eo   = (__hip_bfloat16*)(ws + alloc((size_t)T_ * 2 * HD_ * 2));
  __hip_bfloat16* comb = (__hip_bfloat16*)(ws + alloc((size_t)M8_ * D_ * 2));

  hipMemsetAsync(cnt, 0, 256, stream);
  cvt_bf16_k<<<8192, 256, 0, stream>>>(x, xb);
  tcvt<<<dim3(32, 32, 1), 256, 0, stream>>>(Wm, WmT, 1024, 1024);
  tcvt<<<dim3(32, 32, 1), 256, 0, stream>>>(Wo, WoT, 1024, 1024);
  tcvt<<<dim3(16, 4, 16), 256, 0, stream>>>(W1, W1T, 128, 512);
  tcvt<<<dim3(4, 16, 16), 256, 0, stream>>>(W2, W2T, 512, 128);
  build_wre<<<1024, 128, 0, stream>>>(Wm, bm, emb, Wre, rbias);
  gemm_bt<0><<<512, 256, 0, stream>>>(xb, WmT, bm, hb, M8_, D_, D_);
  route_gemm<<<256, 256, 0, stream>>>(x, Wre, rbias, logits);
  route_topk<<<256, 256, 0, stream>>>(logits, topw, list, cnt);
  prefix_k<<<1, 32, 0, stream>>>(cnt, tileBase);
  expert_mlp3<<<2064, 256, 0, stream>>>(hb, W1T, W2T, b1, b2, topw, list, cnt,
                                        tileBase, eo);
  combine_k<<<4096, 256, 0, stream>>>(eo, comb);
  gemm_bt<1><<<512, 256, 0, stream>>>(comb, WoT, bo, d_out, M8_, D_, D_);
}

// Round 5
// 361.967 us; speedup vs baseline: 2.8838x; 1.1208x over previous
//
#include <hip/hip_runtime.h>
#include <hip/hip_bf16.h>
#include <math.h>

typedef __attribute__((ext_vector_type(8))) short bx8;
typedef __attribute__((ext_vector_type(4))) short sx4;
typedef __attribute__((ext_vector_type(4))) float fx4;

#define D_   1024
#define H_   8
#define E_   16
#define HD_  128
#define I_   512
#define M8_  8192      // BS*L
#define T_   65536     // M8*H

__device__ inline float bf2f(short u) {
  unsigned int x = ((unsigned int)(unsigned short)u) << 16;
  return __builtin_bit_cast(float, x);
}
__device__ inline short f2bf(float f) {
  __hip_bfloat16 h = __float2bfloat16(f);
  return __builtin_bit_cast(short, h);
}

__device__ inline void gload_lds16(const void* g, void* l) {
  __builtin_amdgcn_global_load_lds(
      (const __attribute__((address_space(1))) void*)g,
      (__attribute__((address_space(3))) void*)l, 16, 0, 0);
}

__device__ inline fx4 mfma16(bx8 a, bx8 b, fx4 c) {
  return __builtin_amdgcn_mfma_f32_16x16x32_bf16(a, b, c, 0, 0, 0);
}

// exact-class GELU: erf via Abramowitz-Stegun 7.1.26 (abs err 1.5e-7, ~18 VALU ops)
__device__ inline float gelu_erf(float x) {
  float z = fabsf(x) * 0.70710678118654752f;
  float t = __builtin_amdgcn_rcpf(fmaf(0.3275911f, z, 1.f));
  float p = t * fmaf(t, fmaf(t, fmaf(t, fmaf(t, 1.061405429f, -1.453152027f),
                                     1.421413741f), -0.284496736f), 0.254829592f);
  float er = fmaf(-p, __expf(-z * z), 1.f);
  er = copysignf(er, x);
  return 0.5f * x * (1.f + er);
}

// ---------------- conversions ----------------

__global__ __launch_bounds__(256) void cvt_bf16_k(const float* __restrict__ src,
                                                  __hip_bfloat16* __restrict__ dst) {
  int i = blockIdx.x * 256 + threadIdx.x;
  float4 v = *(const float4*)&src[(size_t)i * 4];
  sx4 o;
  o[0] = f2bf(v.x); o[1] = f2bf(v.y); o[2] = f2bf(v.z); o[3] = f2bf(v.w);
  *(sx4*)((short*)dst + (size_t)i * 4) = o;
}

// batched transpose+convert: dst[b][c][r] = src[b][r][c]
__global__ __launch_bounds__(256) void tcvt(const float* __restrict__ src,
                                            __hip_bfloat16* __restrict__ dst,
                                            int R, int C) {
  __shared__ float tile[32][33];
  int tx = threadIdx.x & 31, ty = threadIdx.x >> 5;
  int r0 = blockIdx.y * 32, c0 = blockIdx.x * 32;
  const float* s = src + (size_t)blockIdx.z * R * C;
  __hip_bfloat16* d = dst + (size_t)blockIdx.z * R * C;
#pragma unroll
  for (int i = ty; i < 32; i += 8) tile[i][tx] = s[(size_t)(r0 + i) * C + c0 + tx];
  __syncthreads();
#pragma unroll
  for (int i = ty; i < 32; i += 8)
    d[(size_t)(c0 + i) * R + r0 + tx] = __float2bfloat16(tile[tx][i]);
}

// ---------------- routing (exact fp32 path) ----------------

__global__ __launch_bounds__(128) void build_wre(const float* __restrict__ Wm,
                                                 const float* __restrict__ bm,
                                                 const float* __restrict__ emb,
                                                 float* __restrict__ Wre,
                                                 float* __restrict__ rbias) {
  __shared__ float wrow[1024];
  __shared__ float embs[2048];
  int tid = threadIdx.x;
  int d = blockIdx.x;
  for (int i = tid; i < 2048; i += 128) embs[i] = emb[i];
  for (int i = tid; i < 1024; i += 128) wrow[i] = Wm[(size_t)d * 1024 + i];
  __syncthreads();
  int eta = tid >> 4, e = tid & 15;
  float acc = 0.f;
  for (int c = 0; c < 128; ++c) acc = fmaf(wrow[eta * 128 + c], embs[c * 16 + e], acc);
  Wre[(size_t)d * 128 + tid] = acc;
  if (blockIdx.x == 0) {
    float b = 0.f;
    for (int c = 0; c < 128; ++c) b = fmaf(bm[eta * 128 + c], embs[c * 16 + e], b);
    rbias[tid] = b;
  }
}

// fused: logits = x @ Wre + rbias (fp32, Wre LDS-staged)  ->  softmax/top-2 -> lists
__global__ __launch_bounds__(256) void route_fused(const float* __restrict__ x,
                                                   const float* __restrict__ Wre,
                                                   const float* __restrict__ rbias,
                                                   float* __restrict__ topw,
                                                   int* __restrict__ list,
                                                   int* __restrict__ cnt) {
  __shared__ float xs[16][64];     // 4 KiB
  __shared__ float wsh[64][128];   // 32 KiB
  __shared__ float ls[16][129];    // 8.25 KiB (pad -> 4-way worst on read)
  __shared__ int lcnt[16];
  __shared__ int gbase[16];
  int tid = threadIdx.x;
  int n = tid & 127, half = tid >> 7;
  int row0 = blockIdx.x * 16;
  if (tid < 16) lcnt[tid] = 0;
  float acc[8];
#pragma unroll
  for (int i = 0; i < 8; ++i) acc[i] = 0.f;

  for (int k0 = 0; k0 < 1024; k0 += 64) {
    __syncthreads();
    {  // stage x chunk: 16 rows x 64 k
      int i4 = tid * 4;
      int row = i4 >> 6, col = i4 & 63;
      *(float4*)&xs[row][col] = *(const float4*)&x[(size_t)(row0 + row) * 1024 + k0 + col];
    }
#pragma unroll
    for (int j = 0; j < 8; ++j) {  // stage Wre chunk: 64 k x 128 n
      int i4 = tid * 4 + j * 1024;
      int row = i4 >> 7, col = i4 & 127;
      *(float4*)&wsh[row][col] = *(const float4*)&Wre[(size_t)(k0 + row) * 128 + col];
    }
    __syncthreads();
#pragma unroll 4
    for (int d4 = 0; d4 < 64; d4 += 4) {
      float w0 = wsh[d4 + 0][n], w1 = wsh[d4 + 1][n];
      float w2 = wsh[d4 + 2][n], w3 = wsh[d4 + 3][n];
#pragma unroll
      for (int i = 0; i < 8; ++i) {
        float4 xv = *(const float4*)&xs[half * 8 + i][d4];
        acc[i] = fmaf(xv.x, w0, acc[i]);
        acc[i] = fmaf(xv.y, w1, acc[i]);
        acc[i] = fmaf(xv.z, w2, acc[i]);
        acc[i] = fmaf(xv.w, w3, acc[i]);
      }
    }
  }
  float rb = rbias[n];
#pragma unroll
  for (int i = 0; i < 8; ++i) ls[half * 8 + i][n] = acc[i] + rb;
  __syncthreads();

  int i1 = 0, i2 = 0, lp1 = 0, lp2 = 0, s = 0;
  if (tid < 128) {
    int lr = tid >> 3, eta = tid & 7;
    s = (row0 + lr) * 8 + eta;
    float v[16];
#pragma unroll
    for (int e = 0; e < 16; ++e) v[e] = ls[lr][eta * 16 + e];
    float v1 = -1e30f, v2 = -1e30f;
#pragma unroll
    for (int e = 0; e < 16; ++e) {
      float val = v[e];
      if (val > v1) { v2 = v1; i2 = i1; v1 = val; i1 = e; }
      else if (val > v2) { v2 = val; i2 = e; }
    }
    float sum = 0.f;
#pragma unroll
    for (int e = 0; e < 16; ++e) sum += expf(v[e] - v1);
    topw[(size_t)2 * s + 0] = 1.0f / sum;
    topw[(size_t)2 * s + 1] = expf(v2 - v1) / sum;
    lp1 = atomicAdd(&lcnt[i1], 1);
    lp2 = atomicAdd(&lcnt[i2], 1);
  }
  __syncthreads();
  if (tid < 16) gbase[tid] = atomicAdd(&cnt[tid], lcnt[tid]);
  __syncthreads();
  if (tid < 128) {
    list[(size_t)i1 * T_ + gbase[i1] + lp1] = 2 * s;
    list[(size_t)i2 * T_ + gbase[i2] + lp2] = 2 * s + 1;
  }
}

// 64-row tile bases per expert (exclusive prefix over ceil(cnt/64))
__global__ void prefix_k(const int* __restrict__ cnt, int* __restrict__ tileBase) {
  if (threadIdx.x == 0 && blockIdx.x == 0) {
    int s = 0;
#pragma unroll
    for (int e = 0; e < 16; ++e) { tileBase[e] = s; s += (cnt[e] + 63) >> 6; }
    tileBase[16] = s;
  }
}

// ---------------- bf16 MFMA GEMM: C = A @ BT^T (+bias), BT is [N][K] ----------------

template <int OUTF32>
__global__ __launch_bounds__(256) void gemm_bt(const __hip_bfloat16* __restrict__ A,
                                               const __hip_bfloat16* __restrict__ BT,
                                               const float* __restrict__ bias,
                                               void* __restrict__ Cout,
                                               int M, int N, int Kd) {
  __shared__ __hip_bfloat16 As[128 * 64];
  __shared__ __hip_bfloat16 Bs[128 * 64];
  int tid = threadIdx.x;
  int lane = tid & 63, w = tid >> 6;
  int nbn = N >> 7;
  // XCD-aware swizzle (gridDim divisible by 8)
  int cpx = gridDim.x >> 3;
  int swz = (blockIdx.x & 7) * cpx + (blockIdx.x >> 3);
  int bm = swz / nbn, bn = swz % nbn;
  int wm = w >> 1, wn = w & 1;
  int r = lane & 15, g = lane >> 4;
  const fx4 fz = {0.f, 0.f, 0.f, 0.f};
  fx4 acc[4][4];
#pragma unroll
  for (int m = 0; m < 4; ++m)
#pragma unroll
    for (int n = 0; n < 4; ++n) acc[m][n] = fz;
  const short* AsS = (const short*)As;
  const short* BsS = (const short*)Bs;
  for (int k0 = 0; k0 < Kd; k0 += 64) {
    __syncthreads();
#pragma unroll
    for (int i = 0; i < 4; ++i) {
      int c = i * 256 + w * 64 + lane;
      int row = c >> 3, ko = (c & 7) * 8;
      gload_lds16(A + (size_t)(bm * 128 + row) * Kd + k0 + ko,
                  (void*)(As + (size_t)(i * 256 + w * 64) * 8));
    }
#pragma unroll
    for (int i = 0; i < 4; ++i) {
      int c = i * 256 + w * 64 + lane;
      int row = c >> 3, ko = (c & 7) * 8;
      gload_lds16(BT + (size_t)(bn * 128 + row) * Kd + k0 + ko,
                  (void*)(Bs + (size_t)(i * 256 + w * 64) * 8));
    }
    __syncthreads();
#pragma unroll
    for (int kb = 0; kb < 2; ++kb) {
      bx8 af[4], bfr[4];
#pragma unroll
      for (int m = 0; m < 4; ++m)
        af[m] = *(const bx8*)(AsS + (wm * 64 + m * 16 + r) * 64 + kb * 32 + g * 8);
#pragma unroll
      for (int n = 0; n < 4; ++n)
        bfr[n] = *(const bx8*)(BsS + (wn * 64 + n * 16 + r) * 64 + kb * 32 + g * 8);
#pragma unroll
      for (int m = 0; m < 4; ++m)
#pragma unroll
        for (int n = 0; n < 4; ++n)
          acc[m][n] = mfma16(af[m], bfr[n], acc[m][n]);
    }
  }
#pragma unroll
  for (int n = 0; n < 4; ++n) {
    int col = bn * 128 + wn * 64 + n * 16 + r;
    float bv = bias[col];
#pragma unroll
    for (int m = 0; m < 4; ++m) {
      int rowb = bm * 128 + wm * 64 + m * 16 + g * 4;
#pragma unroll
      for (int ri = 0; ri < 4; ++ri) {
        float val = acc[m][n][ri] + bv;
        if (OUTF32) ((float*)Cout)[(size_t)(rowb + ri) * N + col] = val;
        else ((__hip_bfloat16*)Cout)[(size_t)(rowb + ri) * N + col] = __float2bfloat16(val);
      }
    }
  }
}

// ---------------- fused per-expert MLP v3 ----------------
// 64 rows/block, 4 waves x 16 rows. Exact tiling via tileBase (no dud blocks).
// LDS exactly 40KiB -> 4 blocks/CU. Swapped GEMM1 (mfma(W1,token)) so hmid
// lands token-major -> vectorized Hc roundtrip (b64 writes / b128 reads).

__global__ __launch_bounds__(256, 4) void expert_mlp3(
    const __hip_bfloat16* __restrict__ h,
    const __hip_bfloat16* __restrict__ W1T,   // [E][512 i][128 d]
    const __hip_bfloat16* __restrict__ W2T,   // [E][128 o][512 i]
    const float* __restrict__ b1,
    const float* __restrict__ b2,
    const float* __restrict__ topw,
    const int* __restrict__ list,
    const int* __restrict__ cnt,
    const int* __restrict__ tileBase,
    __hip_bfloat16* __restrict__ eo) {
  int b = blockIdx.x;
  if (b >= tileBase[16]) return;
  int e = 0;
#pragma unroll
  for (int i = 1; i < 16; ++i) e += (b >= tileBase[i]);
  int tile = b - tileBase[e];
  int cnt_e = cnt[e];
  int base = tile * 64;
  if (base >= cnt_e) return;

  __shared__ short W1c[64 * 128];   // 16 KiB: [64 i][128 d], 16B-unit swizzled
  __shared__ short W2c[128 * 64];   // 16 KiB: [128 o][64 i], swizzled
  __shared__ short Hc[4 * 16 * 64]; //  8 KiB: per-wave [16 t][64 i], swizzled

  int tid = threadIdx.x, lane = tid & 63, wv = tid >> 6;
  int r = lane & 15, g = lane >> 4;
  const int* liste = list + (size_t)e * T_;

  // own-token pid + B-fragments (token data) in registers
  int idx_own = base + wv * 16 + r;
  int p_own = (idx_own < cnt_e) ? liste[idx_own] : -1;
  const short* hS = (const short*)h;
  size_t st = (p_own >= 0) ? (size_t)(p_own >> 1) : 0;
  const short* rp = hS + st * 128 + g * 8;
  bx8 af[4];
#pragma unroll
  for (int kb = 0; kb < 4; ++kb) af[kb] = *(const bx8*)(rp + kb * 32);

  const char* W1S = (const char*)(W1T + (size_t)e * I_ * HD_);
  const char* W2S = (const char*)(W2T + (size_t)e * HD_ * I_);
  const float* b1e = b1 + (size_t)e * I_;
  const float* b2e = b2 + (size_t)e * HD_;
  char* HcW = (char*)Hc + wv * 16 * 128;

  const fx4 fz = {0.f, 0.f, 0.f, 0.f};
  fx4 acc2[8];
#pragma unroll
  for (int n = 0; n < 8; ++n) acc2[n] = fz;

  for (int c = 0; c < 8; ++c) {
    __syncthreads();
    // stage W1 chunk [64 i][128 d] (256B rows, 16 units)
#pragma unroll
    for (int j = 0; j < 4; ++j) {
      int row = wv * 16 + j * 4 + (lane >> 4);
      int u = lane & 15;
      gload_lds16(W1S + (size_t)(c * 64 + row) * 256 + ((u * 16) ^ ((row & 7) << 4)),
                  (char*)W1c + (wv * 16 + j * 4) * 256);
    }
    // stage W2 chunk [128 o][64 i] (128B row-slices of 1024B rows, 8 units)
#pragma unroll
    for (int j = 0; j < 4; ++j) {
      int row = wv * 32 + j * 8 + (lane >> 3);
      int u = lane & 7;
      gload_lds16(W2S + (size_t)row * 1024 + c * 128 + ((u * 16) ^ ((row & 7) << 4)),
                  (char*)W2c + (wv * 32 + j * 8) * 128);
    }
    __syncthreads();

    // GEMM1 (swapped): D1[i][t] = sum_d W1T[i][d] * h[t][d]
    fx4 acc1[4];
#pragma unroll
    for (int ib = 0; ib < 4; ++ib) acc1[ib] = fz;
#pragma unroll
    for (int kb = 0; kb < 4; ++kb) {
#pragma unroll
      for (int ib = 0; ib < 4; ++ib) {
        int irow = ib * 16 + r;
        bx8 a = *(const bx8*)((const char*)W1c + irow * 256 +
                              ((kb * 64 + g * 16) ^ ((irow & 7) << 4)));
        acc1[ib] = mfma16(a, af[kb], acc1[ib]);
      }
    }

    // GELU + vectorized Hc write: lane holds hmid[t=r][i = ib*16+g*4+ri]
#pragma unroll
    for (int ib = 0; ib < 4; ++ib) {
      float4 b1v = *(const float4*)&b1e[c * 64 + ib * 16 + g * 4];
      sx4 ov;
      ov[0] = f2bf(gelu_erf(acc1[ib][0] + b1v.x));
      ov[1] = f2bf(gelu_erf(acc1[ib][1] + b1v.y));
      ov[2] = f2bf(gelu_erf(acc1[ib][2] + b1v.z));
      ov[3] = f2bf(gelu_erf(acc1[ib][3] + b1v.w));
      *(sx4*)(HcW + r * 128 + ((ib * 32 + g * 8) ^ ((r & 7) << 4))) = ov;
    }

    // GEMM2 partial: D2[t][o] += sum_{i in chunk} hmid[t][i] * W2T[o][i]
#pragma unroll
    for (int kb2 = 0; kb2 < 2; ++kb2) {
      bx8 ha = *(const bx8*)(HcW + r * 128 + ((kb2 * 64 + g * 16) ^ ((r & 7) << 4)));
#pragma unroll
      for (int ob = 0; ob < 8; ++ob) {
        int orow = ob * 16 + r;
        bx8 wb = *(const bx8*)((const char*)W2c + orow * 128 +
                               ((kb2 * 64 + g * 16) ^ ((orow & 7) << 4)));
        acc2[ob] = mfma16(ha, wb, acc2[ob]);
      }
    }
  }

  // epilogue: acc2[ob][ri] = eo[t = g*4+ri][o = ob*16+r]
  int pid_ep[4];
  float wt_ep[4];
#pragma unroll
  for (int ri = 0; ri < 4; ++ri) {
    int idx = base + wv * 16 + g * 4 + ri;
    int p = (idx < cnt_e) ? liste[idx] : -1;
    pid_ep[ri] = p;
    wt_ep[ri] = (p >= 0) ? topw[p] : 0.f;
  }
#pragma unroll
  for (int ob = 0; ob < 8; ++ob) {
    float b2v = b2e[ob * 16 + r];
#pragma unroll
    for (int ri = 0; ri < 4; ++ri) {
      int p = pid_ep[ri];
      if (p >= 0) {
        float v = (acc2[ob][ri] + b2v) * wt_ep[ri];
        eo[(size_t)p * 128 + ob * 16 + r] = __float2bfloat16(v);
      }
    }
  }
}

// comb[s][:] = eo[2s][:] + eo[2s+1][:]   (weights already applied)
__global__ __launch_bounds__(256) void combine_k(const __hip_bfloat16* __restrict__ eo,
                                                 __hip_bfloat16* __restrict__ comb) {
  int t = blockIdx.x * 256 + threadIdx.x;
  int s = t >> 4, oo = (t & 15) * 8;
  const short* eS = (const short*)eo;
  bx8 a = *(const bx8*)(eS + (size_t)s * 256 + oo);
  bx8 b = *(const bx8*)(eS + (size_t)s * 256 + 128 + oo);
  bx8 ov;
#pragma unroll
  for (int j = 0; j < 8; ++j) ov[j] = f2bf(bf2f(a[j]) + bf2f(b[j]));
  *(bx8*)((short*)comb + (size_t)s * 128 + oo) = ov;
}

// ---------------- host ----------------

extern "C" void kernel_launch(void* const* d_in, const int* in_sizes, int n_in,
                              void* d_out, int out_size, void* d_ws, size_t ws_size,
                              hipStream_t stream) {
  const float* x   = (const float*)d_in[0];
  const float* Wm  = (const float*)d_in[1];
  const float* bm  = (const float*)d_in[2];
  const float* emb = (const float*)d_in[3];
  const float* W1  = (const float*)d_in[4];
  const float* b1  = (const float*)d_in[5];
  const float* W2  = (const float*)d_in[6];
  const float* b2  = (const float*)d_in[7];
  const float* Wo  = (const float*)d_in[8];
  const float* bo  = (const float*)d_in[9];

  char* ws = (char*)d_ws;
  size_t off = 0;
  auto alloc = [&](size_t b) { size_t r = off; off += (b + 255) & ~(size_t)255; return r; };
  __hip_bfloat16* xb   = (__hip_bfloat16*)(ws + alloc((size_t)M8_ * D_ * 2));
  __hip_bfloat16* WmT  = (__hip_bfloat16*)(ws + alloc((size_t)D_ * D_ * 2));
  __hip_bfloat16* WoT  = (__hip_bfloat16*)(ws + alloc((size_t)D_ * D_ * 2));
  __hip_bfloat16* W1T  = (__hip_bfloat16*)(ws + alloc((size_t)E_ * HD_ * I_ * 2));
  __hip_bfloat16* W2T  = (__hip_bfloat16*)(ws + alloc((size_t)E_ * HD_ * I_ * 2));
  __hip_bfloat16* hb   = (__hip_bfloat16*)(ws + alloc((size_t)M8_ * D_ * 2));
  float* Wre    = (float*)(ws + alloc((size_t)D_ * 128 * 4));
  float* rbias  = (float*)(ws + alloc(512));
  float* topw   = (float*)(ws + alloc((size_t)T_ * 2 * 4));
  int*   cnt    = (int*)(ws + alloc(256));
  int*   tileBase = (int*)(ws + alloc(256));
  int*   list   = (int*)(ws + alloc((size_t)E_ * T_ * 4));
  __hip_bfloat16* eo   = (__hip_bfloat16*)(ws + alloc((size_t)T_ * 2 * HD_ * 2));
  __hip_bfloat16* comb = (__hip_bfloat16*)(ws + alloc((size_t)M8_ * D_ * 2));

  hipMemsetAsync(cnt, 0, 256, stream);
  cvt_bf16_k<<<8192, 256, 0, stream>>>(x, xb);
  tcvt<<<dim3(32, 32, 1), 256, 0, stream>>>(Wm, WmT, 1024, 1024);
  tcvt<<<dim3(32, 32, 1), 256, 0, stream>>>(Wo, WoT, 1024, 1024);
  tcvt<<<dim3(16, 4, 16), 256, 0, stream>>>(W1, W1T, 128, 512);
  tcvt<<<dim3(4, 16, 16), 256, 0, stream>>>(W2, W2T, 512, 128);
  build_wre<<<1024, 128, 0, stream>>>(Wm, bm, emb, Wre, rbias);
  gemm_bt<0><<<512, 256, 0, stream>>>(xb, WmT, bm, hb, M8_, D_, D_);
  route_fused<<<512, 256, 0, stream>>>(x, Wre, rbias, topw, list, cnt);
  prefix_k<<<1, 32, 0, stream>>>(cnt, tileBase);
  expert_mlp3<<<2064, 256, 0, stream>>>(hb, W1T, W2T, b1, b2, topw, list, cnt,
                                        tileBase, eo);
  combine_k<<<4096, 256, 0, stream>>>(eo, comb);
  gemm_bt<1><<<512, 256, 0, stream>>>(comb, WoT, bo, d_out, M8_, D_, D_);
}